// Round 5
// baseline (101.690 us; speedup 1.0000x reference)
//
#include <hip/hip_runtime.h>
#include <math.h>

#define HI 240
#define WI 135
#define NPIX (HI * WI)          // 32400
#define NF 1000
#define NCHUNK 10
#define FCHUNK (NF / NCHUNK)    // 100
#define BLK 256
#define FREC 5                  // float4 per face record
#define TW 8                    // tile width (px)
#define TH 8                    // tile height (px)
#define TX_N 17                 // ceil(135/8)
#define TY_N 30                 // 240/8
#define NTILE (TX_N * TY_N)     // 510
#define TPB 4                   // tiles (waves) per block
#define NBX ((NTILE + TPB - 1) / TPB)   // 128

// Face record in LDS (5 x float4):
//   r0 = (p0x, p0y, e0x, e0y)   edge 0: v0 -> v1
//   r1 = (p1x, p1y, e1x, e1y)   edge 1: v1 -> v2
//   r2 = (p2x, p2y, e2x, e2y)   edge 2: v2 -> v0
//   r3 = (rden0, rden1, rden2, tz_valid)
//   r4 = (bbox xmin, ymin, xmax, ymax)

__device__ __forceinline__ void project(float x, float y, float z,
                                        float& px, float& py) {
#pragma clang fp contract(off)
    // Bitwise-mirrors ref: z=max(v_z,1e-6); px=(1000*(-x)/z + 512)/1024*W; etc.
    float zc = fmaxf(z, 1e-6f);
    px = ((1000.0f * (-x)) / zc + 512.0f) / 1024.0f * (float)WI;
    py = ((1000.0f * (-y)) / zc + 512.0f) / 1024.0f * (float)HI;
}

// R5 structure notes (from R2/R4 post-mortems):
//  - NO device-scope fences, NO global atomics in the hot kernel. Each
//    (tile, chunk) block exclusively owns ws[chunk][its 64 pixels], so the
//    partial sum is a plain coalesced store. Kernel boundary gives fin
//    visibility for free.
//  - No prep kernel: each block rebuilds its chunk's 100 face records from
//    verts/faces directly into LDS (L2-broadcast reads, ~1 round), removing
//    a dispatch and the frec global round-trip.
__global__ __launch_bounds__(BLK) void sil_kernel(
    const float* __restrict__ verts, const int* __restrict__ faces,
    float* __restrict__ ws, float* __restrict__ out)
{
    __shared__ float4 sf[FCHUNK * FREC];   // 8000 B

    // out[0] zeroed here (harness poisons 0xAA); only fin touches it later.
    if (blockIdx.x == 0 && blockIdx.y == 0 && threadIdx.x == 0) out[0] = 0.0f;

    // ---- build this chunk's face records in LDS ----
    {
        int f = threadIdx.x;
        if (f < FCHUNK) {
#pragma clang fp contract(off)
            int g = blockIdx.y * FCHUNK + f;
            int i0 = faces[3 * g + 0], i1 = faces[3 * g + 1], i2 = faces[3 * g + 2];
            float x0 = verts[3 * i0 + 0], y0 = verts[3 * i0 + 1], z0 = verts[3 * i0 + 2];
            float x1 = verts[3 * i1 + 0], y1 = verts[3 * i1 + 1], z1 = verts[3 * i1 + 2];
            float x2 = verts[3 * i2 + 0], y2 = verts[3 * i2 + 1], z2 = verts[3 * i2 + 2];

            float p0x, p0y, p1x, p1y, p2x, p2y;
            project(x0, y0, z0, p0x, p0y);
            project(x1, y1, z1, p1x, p1y);
            project(x2, y2, z2, p2x, p2y);

            float e0x = p1x - p0x, e0y = p1y - p0y;
            float e1x = p2x - p1x, e1y = p2y - p1y;
            float e2x = p0x - p2x, e2y = p0y - p2y;
            float den0 = (e0x * e0x + e0y * e0y) + 1e-12f;
            float den1 = (e1x * e1x + e1y * e1y) + 1e-12f;
            float den2 = (e2x * e2x + e2y * e2y) + 1e-12f;

            float tz = ((z0 + z1) + z2) / 3.0f;
            bool tzok = tz > 1e-6f;

            // Pathology rule (provable): fp cross sign flip outside
            // bbox+0.3px needs two simultaneously-ambiguous crosses; safe
            // iff area2 >= 4e-3*lmax^2 and lmax <= 2000px. Unsafe faces get
            // an infinite bbox (evaluated everywhere, bitwise-matching).
            float area2 = fabsf(e0x * e1y - e0y * e1x);
            float l2max = fmaxf(den0, fmaxf(den1, den2));
            bool dup = (i0 == i1) || (i1 == i2) || (i2 == i0);
            bool patho = dup || (area2 < 4.0e-3f * l2max) || (l2max > 4.0e6f);

            float bx0, by0, bx1, by1;
            if (!tzok) {               // contribution exactly zero everywhere
                bx0 = 1e30f; by0 = 1e30f; bx1 = -1e30f; by1 = -1e30f;
            } else if (patho) {        // always evaluate
                bx0 = -1e30f; by0 = -1e30f; bx1 = 1e30f; by1 = 1e30f;
            } else {
                // 0.3 px margin >= sqrt(BLUR)=0.0304 blur band + fp band
                bx0 = fminf(p0x, fminf(p1x, p2x)) - 0.3f;
                by0 = fminf(p0y, fminf(p1y, p2y)) - 0.3f;
                bx1 = fmaxf(p0x, fmaxf(p1x, p2x)) + 0.3f;
                by1 = fmaxf(p0y, fmaxf(p1y, p2y)) + 0.3f;
            }

            sf[FREC * f + 0] = make_float4(p0x, p0y, e0x, e0y);
            sf[FREC * f + 1] = make_float4(p1x, p1y, e1x, e1y);
            sf[FREC * f + 2] = make_float4(p2x, p2y, e2x, e2y);
            sf[FREC * f + 3] = make_float4(1.0f / den0, 1.0f / den1, 1.0f / den2,
                                           tzok ? 1.0f : 0.0f);
            sf[FREC * f + 4] = make_float4(bx0, by0, bx1, by1);
        }
    }
    __syncthreads();

    int wave = threadIdx.x >> 6, lane = threadIdx.x & 63;
    int tile = blockIdx.x * TPB + wave;
    if (tile >= NTILE) return;

    int ty = tile / TX_N, tx = tile - ty * TX_N;
    int col = tx * TW + (lane & 7);
    int row = ty * TH + (lane >> 3);
    bool live = col < WI;                  // x-tail tiles partially valid
    int q = row * WI + col;
    float px = (float)col + 0.5f;
    float py = (float)row + 0.5f;
    // wave-uniform 8x8 tile rect
    float wx0 = (float)(tx * TW) + 0.5f, wx1 = (float)(tx * TW + TW - 1) + 0.5f;
    float wy0 = (float)(ty * TH) + 0.5f, wy1 = (float)(ty * TH + TH - 1) + 0.5f;

    float sum = 0.0f;
    for (int r = 0; r < (FCHUNK + 63) / 64; ++r) {
        int fl = r * 64 + lane;
        bool ov = false;
        if (fl < FCHUNK) {
            float4 bb = sf[FREC * fl + 4];
            ov = !(bb.x > wx1 || bb.z < wx0 || bb.y > wy1 || bb.w < wy0);
        }
        unsigned long long m = __ballot(ov);

        while (m) {
            int fb = __ffsll((long long)m) - 1;
            m &= m - 1;
            int f = r * 64 + fb;

            float4 r0v = sf[FREC * f + 0];   // uniform addr -> broadcast
            float4 r1v = sf[FREC * f + 1];
            float4 r2v = sf[FREC * f + 2];
            float4 dv  = sf[FREC * f + 3];

            float a0x = px - r0v.x, a0y = py - r0v.y;
            float a1x = px - r1v.x, a1y = py - r1v.y;
            float a2x = px - r2v.x, a2y = py - r2v.y;

            float c0, c1, c2;
            {
#pragma clang fp contract(off)
                // bitwise-match ref (sign-test cliff)
                c0 = r0v.z * a0y - r0v.w * a0x;
                c1 = r1v.z * a1y - r1v.w * a1x;
                c2 = r2v.z * a2y - r2v.w * a2x;
            }
            bool pos = (c0 >= 0.0f) & (c1 >= 0.0f) & (c2 >= 0.0f);
            bool neg = (c0 <= 0.0f) & (c1 <= 0.0f) & (c2 <= 0.0f);

            // smooth region: FMA + reciprocal are fine (2e-2 slack)
            float t0 = fminf(fmaxf((a0x * r0v.z + a0y * r0v.w) * dv.x, 0.0f), 1.0f);
            float t1 = fminf(fmaxf((a1x * r1v.z + a1y * r1v.w) * dv.y, 0.0f), 1.0f);
            float t2 = fminf(fmaxf((a2x * r2v.z + a2y * r2v.w) * dv.z, 0.0f), 1.0f);
            float u0x = a0x - t0 * r0v.z, u0y = a0y - t0 * r0v.w;
            float u1x = a1x - t1 * r1v.z, u1y = a1y - t1 * r1v.w;
            float u2x = a2x - t2 * r2v.z, u2y = a2y - t2 * r2v.w;
            float d20 = u0x * u0x + u0y * u0y;
            float d21 = u1x * u1x + u1y * u1y;
            float d22 = u2x * u2x + u2y * u2y;
            float d2m = fminf(d20, fminf(d21, d22));

            bool inside = pos | neg;
            // contribution = log1p(-sigmoid(-sd/SIGMA)) = -softplus(uu)
            float uu = (inside ? d2m : -d2m) * 1.0e4f;
            bool valid = (dv.w != 0.0f) & (inside | (d2m <= 9.2102404e-4f));
            // wave-coherent fast path: interior pixels have uu >> 16, where
            // softplus(uu) = uu to < 1.2e-7
            float sp;
            if (uu > 16.0f) sp = uu;
            else sp = fmaxf(uu, 0.0f) + __logf(1.0f + __expf(-fabsf(uu)));
            sum -= valid ? sp : 0.0f;
        }
    }
    // exclusive ownership of (chunk, pixel) -> plain coalesced store
    if (live) ws[(size_t)blockIdx.y * NPIX + q] = sum;
}

__global__ __launch_bounds__(BLK) void fin_kernel(
    const float* __restrict__ ws, const float* __restrict__ gt,
    float* __restrict__ out)
{
    __shared__ float wsum[BLK / 64];
    int q = blockIdx.x * BLK + threadIdx.x;
    float c = 0.0f;
    if (q < NPIX) {
        float s = 0.0f;
        for (int ch = 0; ch < NCHUNK; ++ch) s += ws[(size_t)ch * NPIX + q];
        float alpha = 1.0f - __expf(s);    // exp(-inf/big-neg) -> 0 -> alpha=1
        out[1 + q] = alpha;
        c = fabsf(alpha - gt[q]);
    }
    for (int off = 32; off > 0; off >>= 1) c += __shfl_down(c, off, 64);
    if ((threadIdx.x & 63) == 0) wsum[threadIdx.x >> 6] = c;
    __syncthreads();
    if (threadIdx.x == 0) {
        float s = 0.0f;
        for (int w = 0; w < BLK / 64; ++w) s += wsum[w];
        atomicAdd(&out[0], s * (1.0f / (float)NPIX));   // out[0] zeroed by sil
    }
}

extern "C" void kernel_launch(void* const* d_in, const int* in_sizes, int n_in,
                              void* d_out, int out_size, void* d_ws, size_t ws_size,
                              hipStream_t stream)
{
    const float* verts = (const float*)d_in[0];
    const float* gt    = (const float*)d_in[1];
    const int*   faces = (const int*)d_in[2];
    float* out = (float*)d_out;          // out[0]=loss, out[1..]=sil (H*W)
    float* ws  = (float*)d_ws;           // NCHUNK * NPIX floats = 1.3 MB partials

    dim3 sgrid(NBX, NCHUNK);             // 128 x 10 = 1280 blocks
    sil_kernel<<<sgrid, BLK, 0, stream>>>(verts, faces, ws, out);

    fin_kernel<<<(NPIX + BLK - 1) / BLK, BLK, 0, stream>>>(ws, gt, out);
}

// Round 6
// 76.621 us; speedup vs baseline: 1.3272x; 1.3272x over previous
//
#include <hip/hip_runtime.h>
#include <math.h>

#define HI 240
#define WI 135
#define NPIX (HI * WI)          // 32400
#define NF 1000
#define NCHUNK 10
#define FCHUNK (NF / NCHUNK)    // 100
#define BLK 256
#define FREC 4                  // float4 per face record (bbox moved to SoA)
#define TW 8                    // tile width (px)
#define TH 8                    // tile height (px)
#define TX_N 17                 // ceil(135/8)
#define TY_N 30                 // 240/8
#define NTILE (TX_N * TY_N)     // 510
#define TPB 4                   // tiles (waves) per block
#define NBX ((NTILE + TPB - 1) / TPB)   // 128

// Face record in LDS (4 x float4):
//   r0 = (p0x, p0y, e0x, e0y)   edge 0: v0 -> v1
//   r1 = (p1x, p1y, e1x, e1y)   edge 1: v1 -> v2
//   r2 = (p2x, p2y, e2x, e2y)   edge 2: v2 -> v0
//   r3 = (rden0, rden1, rden2, tz_valid)
// Bboxes in SoA float arrays (4 B stride -> conflict-free lane gather).

__device__ __forceinline__ void project(float x, float y, float z,
                                        float& px, float& py) {
#pragma clang fp contract(off)
    // Bitwise-mirrors ref: z=max(v_z,1e-6); px=(1000*(-x)/z + 512)/1024*W; etc.
    float zc = fmaxf(z, 1e-6f);
    px = ((1000.0f * (-x)) / zc + 512.0f) / 1024.0f * (float)WI;
    py = ((1000.0f * (-y)) / zc + 512.0f) / 1024.0f * (float)HI;
}

// Structure notes (R2/R4/R5 post-mortems):
//  - NO device-scope fences / global atomics in the hot path (R2: fence storm).
//  - Exclusive (tile,chunk) -> plain store into ws partials (R5).
//  - R6: alpha-saturation early exit. All contributions are <= 0; once every
//    live lane's partial sum <= -30, alpha = 1-exp(S) is bitwise 1.0f for BOTH
//    ref and kernel (exp(-30) < 1/2 ulp(1)), so the wave abandons remaining
//    faces. This bounds the straggler center-tile waves that set R5's 42 us.
__global__ __launch_bounds__(BLK) void sil_kernel(
    const float* __restrict__ verts, const int* __restrict__ faces,
    float* __restrict__ ws, float* __restrict__ out)
{
    __shared__ float4 sf[FCHUNK * FREC];   // 6400 B
    __shared__ float sbx0[FCHUNK], sby0[FCHUNK], sbx1[FCHUNK], sby1[FCHUNK];

    // out[0] zeroed here (harness poisons 0xAA); only fin touches it later.
    if (blockIdx.x == 0 && blockIdx.y == 0 && threadIdx.x == 0) out[0] = 0.0f;

    // ---- build this chunk's face records in LDS ----
    {
        int f = threadIdx.x;
        if (f < FCHUNK) {
#pragma clang fp contract(off)
            int g = blockIdx.y * FCHUNK + f;
            int i0 = faces[3 * g + 0], i1 = faces[3 * g + 1], i2 = faces[3 * g + 2];
            float x0 = verts[3 * i0 + 0], y0 = verts[3 * i0 + 1], z0 = verts[3 * i0 + 2];
            float x1 = verts[3 * i1 + 0], y1 = verts[3 * i1 + 1], z1 = verts[3 * i1 + 2];
            float x2 = verts[3 * i2 + 0], y2 = verts[3 * i2 + 1], z2 = verts[3 * i2 + 2];

            float p0x, p0y, p1x, p1y, p2x, p2y;
            project(x0, y0, z0, p0x, p0y);
            project(x1, y1, z1, p1x, p1y);
            project(x2, y2, z2, p2x, p2y);

            float e0x = p1x - p0x, e0y = p1y - p0y;
            float e1x = p2x - p1x, e1y = p2y - p1y;
            float e2x = p0x - p2x, e2y = p0y - p2y;
            float den0 = (e0x * e0x + e0y * e0y) + 1e-12f;
            float den1 = (e1x * e1x + e1y * e1y) + 1e-12f;
            float den2 = (e2x * e2x + e2y * e2y) + 1e-12f;

            float tz = ((z0 + z1) + z2) / 3.0f;
            bool tzok = tz > 1e-6f;

            // Pathology rule (provable): fp cross sign flip outside bbox+0.3px
            // needs two simultaneously-ambiguous crosses; safe iff
            // area2 >= 4e-3*lmax^2 and lmax <= 2000px. Unsafe faces get an
            // infinite bbox (evaluated everywhere, bitwise-matching).
            float area2 = fabsf(e0x * e1y - e0y * e1x);
            float l2max = fmaxf(den0, fmaxf(den1, den2));
            bool dup = (i0 == i1) || (i1 == i2) || (i2 == i0);
            bool patho = dup || (area2 < 4.0e-3f * l2max) || (l2max > 4.0e6f);

            float bx0, by0, bx1, by1;
            if (!tzok) {               // contribution exactly zero everywhere
                bx0 = 1e30f; by0 = 1e30f; bx1 = -1e30f; by1 = -1e30f;
            } else if (patho) {        // always evaluate
                bx0 = -1e30f; by0 = -1e30f; bx1 = 1e30f; by1 = 1e30f;
            } else {
                // 0.3 px margin >= sqrt(BLUR)=0.0304 blur band + fp band
                bx0 = fminf(p0x, fminf(p1x, p2x)) - 0.3f;
                by0 = fminf(p0y, fminf(p1y, p2y)) - 0.3f;
                bx1 = fmaxf(p0x, fmaxf(p1x, p2x)) + 0.3f;
                by1 = fmaxf(p0y, fmaxf(p1y, p2y)) + 0.3f;
            }

            sf[FREC * f + 0] = make_float4(p0x, p0y, e0x, e0y);
            sf[FREC * f + 1] = make_float4(p1x, p1y, e1x, e1y);
            sf[FREC * f + 2] = make_float4(p2x, p2y, e2x, e2y);
            sf[FREC * f + 3] = make_float4(1.0f / den0, 1.0f / den1, 1.0f / den2,
                                           tzok ? 1.0f : 0.0f);
            sbx0[f] = bx0; sby0[f] = by0; sbx1[f] = bx1; sby1[f] = by1;
        }
    }
    __syncthreads();

    int wave = threadIdx.x >> 6, lane = threadIdx.x & 63;
    int tile = blockIdx.x * TPB + wave;
    if (tile >= NTILE) return;

    int ty = tile / TX_N, tx = tile - ty * TX_N;
    int col = tx * TW + (lane & 7);
    int row = ty * TH + (lane >> 3);
    bool live = col < WI;                  // x-tail tiles partially valid
    int q = row * WI + col;
    float px = (float)col + 0.5f;
    float py = (float)row + 0.5f;
    // wave-uniform 8x8 tile rect
    float wx0 = (float)(tx * TW) + 0.5f, wx1 = (float)(tx * TW + TW - 1) + 0.5f;
    float wy0 = (float)(ty * TH) + 0.5f, wy1 = (float)(ty * TH + TH - 1) + 0.5f;

    // dead lanes start saturated so they never block the early-exit ballot
    float sum = live ? 0.0f : -1e30f;
    bool done = false;

    for (int r = 0; r < (FCHUNK + 63) / 64 && !done; ++r) {
        int fl = r * 64 + lane;
        bool ov = false;
        if (fl < FCHUNK) {
            ov = !(sbx0[fl] > wx1 || sbx1[fl] < wx0 ||
                   sby0[fl] > wy1 || sby1[fl] < wy0);
        }
        unsigned long long m = __ballot(ov);

        while (m) {
            int fb = __ffsll((long long)m) - 1;
            m &= m - 1;
            int f = r * 64 + fb;

            float4 r0v = sf[FREC * f + 0];   // uniform addr -> broadcast
            float4 r1v = sf[FREC * f + 1];
            float4 r2v = sf[FREC * f + 2];
            float4 dv  = sf[FREC * f + 3];

            float a0x = px - r0v.x, a0y = py - r0v.y;
            float a1x = px - r1v.x, a1y = py - r1v.y;
            float a2x = px - r2v.x, a2y = py - r2v.y;

            float c0, c1, c2;
            {
#pragma clang fp contract(off)
                // bitwise-match ref (sign-test cliff)
                c0 = r0v.z * a0y - r0v.w * a0x;
                c1 = r1v.z * a1y - r1v.w * a1x;
                c2 = r2v.z * a2y - r2v.w * a2x;
            }
            bool pos = (c0 >= 0.0f) & (c1 >= 0.0f) & (c2 >= 0.0f);
            bool neg = (c0 <= 0.0f) & (c1 <= 0.0f) & (c2 <= 0.0f);

            // smooth region: FMA + reciprocal are fine (2e-2 slack)
            float t0 = fminf(fmaxf((a0x * r0v.z + a0y * r0v.w) * dv.x, 0.0f), 1.0f);
            float t1 = fminf(fmaxf((a1x * r1v.z + a1y * r1v.w) * dv.y, 0.0f), 1.0f);
            float t2 = fminf(fmaxf((a2x * r2v.z + a2y * r2v.w) * dv.z, 0.0f), 1.0f);
            float u0x = a0x - t0 * r0v.z, u0y = a0y - t0 * r0v.w;
            float u1x = a1x - t1 * r1v.z, u1y = a1y - t1 * r1v.w;
            float u2x = a2x - t2 * r2v.z, u2y = a2y - t2 * r2v.w;
            float d20 = u0x * u0x + u0y * u0y;
            float d21 = u1x * u1x + u1y * u1y;
            float d22 = u2x * u2x + u2y * u2y;
            float d2m = fminf(d20, fminf(d21, d22));

            bool inside = pos | neg;
            // contribution = log1p(-sigmoid(-sd/SIGMA)) = -softplus(uu)
            float uu = (inside ? d2m : -d2m) * 1.0e4f;
            bool valid = (dv.w != 0.0f) & (inside | (d2m <= 9.2102404e-4f));
            // wave-coherent fast path: softplus(uu)=uu to <1.2e-7 for uu>16
            float sp;
            if (uu > 16.0f) sp = uu;
            else sp = fmaxf(uu, 0.0f) + __logf(1.0f + __expf(-fabsf(uu)));
            sum -= valid ? sp : 0.0f;

            // alpha saturation: every lane <= -30 -> 1-exp(S) is bitwise 1.0f
            // for both ref and kernel; remaining faces can't change anything.
            if (__ballot(sum <= -30.0f) == 0xFFFFFFFFFFFFFFFFull) {
                done = true;
                break;
            }
        }
    }
    // exclusive ownership of (chunk, pixel) -> plain coalesced store
    if (live) ws[(size_t)blockIdx.y * NPIX + q] = sum;
}

__global__ __launch_bounds__(BLK) void fin_kernel(
    const float* __restrict__ ws, const float* __restrict__ gt,
    float* __restrict__ out)
{
    __shared__ float wsum[BLK / 64];
    int q = blockIdx.x * BLK + threadIdx.x;
    float c = 0.0f;
    if (q < NPIX) {
        float s = 0.0f;
        for (int ch = 0; ch < NCHUNK; ++ch) s += ws[(size_t)ch * NPIX + q];
        float alpha = 1.0f - __expf(s);    // exp(very negative) -> 0 -> alpha=1
        out[1 + q] = alpha;
        c = fabsf(alpha - gt[q]);
    }
    for (int off = 32; off > 0; off >>= 1) c += __shfl_down(c, off, 64);
    if ((threadIdx.x & 63) == 0) wsum[threadIdx.x >> 6] = c;
    __syncthreads();
    if (threadIdx.x == 0) {
        float s = 0.0f;
        for (int w = 0; w < BLK / 64; ++w) s += wsum[w];
        atomicAdd(&out[0], s * (1.0f / (float)NPIX));   // out[0] zeroed by sil
    }
}

extern "C" void kernel_launch(void* const* d_in, const int* in_sizes, int n_in,
                              void* d_out, int out_size, void* d_ws, size_t ws_size,
                              hipStream_t stream)
{
    const float* verts = (const float*)d_in[0];
    const float* gt    = (const float*)d_in[1];
    const int*   faces = (const int*)d_in[2];
    float* out = (float*)d_out;          // out[0]=loss, out[1..]=sil (H*W)
    float* ws  = (float*)d_ws;           // NCHUNK * NPIX floats = 1.3 MB partials

    dim3 sgrid(NBX, NCHUNK);             // 128 x 10 = 1280 blocks
    sil_kernel<<<sgrid, BLK, 0, stream>>>(verts, faces, ws, out);

    fin_kernel<<<(NPIX + BLK - 1) / BLK, BLK, 0, stream>>>(ws, gt, out);
}

// Round 7
// 72.413 us; speedup vs baseline: 1.4043x; 1.0581x over previous
//
#include <hip/hip_runtime.h>
#include <math.h>

#define HI 240
#define WI 135
#define NPIX (HI * WI)          // 32400
#define NF 1000
#define NCHUNK 10
#define FCHUNK (NF / NCHUNK)    // 100
#define BLK 256
#define FREC 4                  // float4 per face record (eval AoS)
#define TW 8                    // tile width (px)
#define TH 8                    // tile height (px)
#define TX_N 17                 // ceil(135/8)
#define TY_N 30                 // 240/8
#define NTILE (TX_N * TY_N)     // 510
#define TPB 4                   // tiles (waves) per block
#define NBX ((NTILE + TPB - 1) / TPB)   // 128

// Eval record in LDS (4 x float4), read via wave-uniform broadcast:
//   r0 = (p0x, p0y, e0x, e0y)   edge 0: v0 -> v1
//   r1 = (p1x, p1y, e1x, e1y)   edge 1: v1 -> v2
//   r2 = (p2x, p2y, e2x, e2y)   edge 2: v2 -> v0
//   r3 = (rden0, rden1, rden2, tz_valid)
// Scan-phase data (bbox + SAT) in SoA float arrays: 4 B stride -> conflict-
// free per-lane gather. SAT edge vectors are pre-multiplied by the triangle
// orientation sign so "triangle side" is always positive.

__device__ __forceinline__ void project(float x, float y, float z,
                                        float& px, float& py) {
#pragma clang fp contract(off)
    // Bitwise-mirrors ref: z=max(v_z,1e-6); px=(1000*(-x)/z + 512)/1024*W; etc.
    float zc = fmaxf(z, 1e-6f);
    px = ((1000.0f * (-x)) / zc + 512.0f) / 1024.0f * (float)WI;
    py = ((1000.0f * (-y)) / zc + 512.0f) / 1024.0f * (float)HI;
}

// One face evaluation, bitwise-matching the reference arithmetic on the
// sign-test cliff (crosses), fast-math on the smooth parts. Returns the
// non-negative amount to subtract from the pixel's log-sum.
__device__ __forceinline__ float eval_face(const float4* sf, int f,
                                           float px, float py)
{
    float4 r0v = sf[FREC * f + 0];   // uniform addr -> LDS broadcast
    float4 r1v = sf[FREC * f + 1];
    float4 r2v = sf[FREC * f + 2];
    float4 dv  = sf[FREC * f + 3];

    float a0x = px - r0v.x, a0y = py - r0v.y;
    float a1x = px - r1v.x, a1y = py - r1v.y;
    float a2x = px - r2v.x, a2y = py - r2v.y;

    float c0, c1, c2;
    {
#pragma clang fp contract(off)
        c0 = r0v.z * a0y - r0v.w * a0x;
        c1 = r1v.z * a1y - r1v.w * a1x;
        c2 = r2v.z * a2y - r2v.w * a2x;
    }
    bool pos = (c0 >= 0.0f) & (c1 >= 0.0f) & (c2 >= 0.0f);
    bool neg = (c0 <= 0.0f) & (c1 <= 0.0f) & (c2 <= 0.0f);

    float t0 = fminf(fmaxf((a0x * r0v.z + a0y * r0v.w) * dv.x, 0.0f), 1.0f);
    float t1 = fminf(fmaxf((a1x * r1v.z + a1y * r1v.w) * dv.y, 0.0f), 1.0f);
    float t2 = fminf(fmaxf((a2x * r2v.z + a2y * r2v.w) * dv.z, 0.0f), 1.0f);
    float u0x = a0x - t0 * r0v.z, u0y = a0y - t0 * r0v.w;
    float u1x = a1x - t1 * r1v.z, u1y = a1y - t1 * r1v.w;
    float u2x = a2x - t2 * r2v.z, u2y = a2y - t2 * r2v.w;
    float d20 = u0x * u0x + u0y * u0y;
    float d21 = u1x * u1x + u1y * u1y;
    float d22 = u2x * u2x + u2y * u2y;
    float d2m = fminf(d20, fminf(d21, d22));

    bool inside = pos | neg;
    float uu = (inside ? d2m : -d2m) * 1.0e4f;
    bool valid = (dv.w != 0.0f) & (inside | (d2m <= 9.2102404e-4f));
    float sp;
    if (uu > 16.0f) sp = uu;     // softplus(uu)=uu to <1.2e-7
    else sp = fmaxf(uu, 0.0f) + __logf(1.0f + __expf(-fabsf(uu)));
    return valid ? sp : 0.0f;
}

// Structure notes (R2/R4/R5/R6 post-mortems):
//  - NO device-scope fences / global atomics in the hot path (R2 fence storm).
//  - Exclusive (tile,chunk) ownership -> plain store into ws partials (R5).
//  - Alpha-saturation early exit: all-lanes sum <= -30 -> alpha bitwise 1.0f
//    for both ref and kernel -> abandon remaining faces (R6, -25us).
//  - R7: 2-wide ILP in the serial eval loop + exact SAT tile/triangle cull
//    in the lane-parallel scan (separated-by-an-edge-line faces contribute
//    exactly 0: d2 > 0.3^2 >> BLUR, and neg can't pass since
//    c0+c1+c2 = 2*area >> 3*fp_eps for non-patho faces).
__global__ __launch_bounds__(BLK) void sil_kernel(
    const float* __restrict__ verts, const int* __restrict__ faces,
    float* __restrict__ ws, float* __restrict__ out)
{
    __shared__ float4 sf[FCHUNK * FREC];                       // 6400 B
    __shared__ float sbx0[FCHUNK], sby0[FCHUNK], sbx1[FCHUNK], sby1[FCHUNK];
    __shared__ float sPx[3][FCHUNK], sPy[3][FCHUNK];           // edge origins
    __shared__ float sEx[3][FCHUNK], sEy[3][FCHUNK];           // signed edges
    __shared__ float sRd[3][FCHUNK];                           // 1/den
    __shared__ float sFlag[FCHUNK];                            // 0/1/2

    // out[0] zeroed here (harness poisons 0xAA); only fin touches it later.
    if (blockIdx.x == 0 && blockIdx.y == 0 && threadIdx.x == 0) out[0] = 0.0f;

    // ---- build this chunk's face records in LDS ----
    {
        int f = threadIdx.x;
        if (f < FCHUNK) {
#pragma clang fp contract(off)
            int g = blockIdx.y * FCHUNK + f;
            int i0 = faces[3 * g + 0], i1 = faces[3 * g + 1], i2 = faces[3 * g + 2];
            float x0 = verts[3 * i0 + 0], y0 = verts[3 * i0 + 1], z0 = verts[3 * i0 + 2];
            float x1 = verts[3 * i1 + 0], y1 = verts[3 * i1 + 1], z1 = verts[3 * i1 + 2];
            float x2 = verts[3 * i2 + 0], y2 = verts[3 * i2 + 1], z2 = verts[3 * i2 + 2];

            float p0x, p0y, p1x, p1y, p2x, p2y;
            project(x0, y0, z0, p0x, p0y);
            project(x1, y1, z1, p1x, p1y);
            project(x2, y2, z2, p2x, p2y);

            float e0x = p1x - p0x, e0y = p1y - p0y;
            float e1x = p2x - p1x, e1y = p2y - p1y;
            float e2x = p0x - p2x, e2y = p0y - p2y;
            float den0 = (e0x * e0x + e0y * e0y) + 1e-12f;
            float den1 = (e1x * e1x + e1y * e1y) + 1e-12f;
            float den2 = (e2x * e2x + e2y * e2y) + 1e-12f;
            float rd0 = 1.0f / den0, rd1 = 1.0f / den1, rd2 = 1.0f / den2;

            float tz = ((z0 + z1) + z2) / 3.0f;
            bool tzok = tz > 1e-6f;

            // Pathology rule (provable): fp cross sign flip outside bbox+0.3px
            // needs two simultaneously-ambiguous crosses; safe iff
            // area2 >= 4e-3*lmax^2 and lmax <= 2000px.
            float orient = e0x * e1y - e0y * e1x;   // 2*signed area
            float area2 = fabsf(orient);
            float l2max = fmaxf(den0, fmaxf(den1, den2));
            bool dup = (i0 == i1) || (i1 == i2) || (i2 == i0);
            bool patho = dup || (area2 < 4.0e-3f * l2max) || (l2max > 4.0e6f);

            float bx0, by0, bx1, by1, flag;
            if (!tzok) {               // contribution exactly zero everywhere
                bx0 = 1e30f; by0 = 1e30f; bx1 = -1e30f; by1 = -1e30f; flag = 0.0f;
            } else if (patho) {        // always evaluate, no SAT cull
                bx0 = -1e30f; by0 = -1e30f; bx1 = 1e30f; by1 = 1e30f; flag = 2.0f;
            } else {
                // 0.3 px margin >= sqrt(BLUR)=0.0304 blur band + fp band
                bx0 = fminf(p0x, fminf(p1x, p2x)) - 0.3f;
                by0 = fminf(p0y, fminf(p1y, p2y)) - 0.3f;
                bx1 = fmaxf(p0x, fmaxf(p1x, p2x)) + 0.3f;
                by1 = fmaxf(p0y, fmaxf(p1y, p2y)) + 0.3f;
                flag = 1.0f;
            }

            sf[FREC * f + 0] = make_float4(p0x, p0y, e0x, e0y);
            sf[FREC * f + 1] = make_float4(p1x, p1y, e1x, e1y);
            sf[FREC * f + 2] = make_float4(p2x, p2y, e2x, e2y);
            sf[FREC * f + 3] = make_float4(rd0, rd1, rd2, tzok ? 1.0f : 0.0f);
            sbx0[f] = bx0; sby0[f] = by0; sbx1[f] = bx1; sby1[f] = by1;
            sFlag[f] = flag;
            float sgn = (orient >= 0.0f) ? 1.0f : -1.0f;  // triangle side -> +
            sPx[0][f] = p0x; sPy[0][f] = p0y; sEx[0][f] = sgn * e0x; sEy[0][f] = sgn * e0y; sRd[0][f] = rd0;
            sPx[1][f] = p1x; sPy[1][f] = p1y; sEx[1][f] = sgn * e1x; sEy[1][f] = sgn * e1y; sRd[1][f] = rd1;
            sPx[2][f] = p2x; sPy[2][f] = p2y; sEx[2][f] = sgn * e2x; sEy[2][f] = sgn * e2y; sRd[2][f] = rd2;
        }
    }
    __syncthreads();

    int wave = threadIdx.x >> 6, lane = threadIdx.x & 63;
    int tile = blockIdx.x * TPB + wave;
    if (tile >= NTILE) return;

    int ty = tile / TX_N, tx = tile - ty * TX_N;
    int col = tx * TW + (lane & 7);
    int row = ty * TH + (lane >> 3);
    bool live = col < WI;                  // x-tail tiles partially valid
    int q = row * WI + col;
    float px = (float)col + 0.5f;
    float py = (float)row + 0.5f;
    // wave-uniform 8x8 tile rect (pixel centers)
    float wx0 = (float)(tx * TW) + 0.5f, wx1 = (float)(tx * TW + TW - 1) + 0.5f;
    float wy0 = (float)(ty * TH) + 0.5f, wy1 = (float)(ty * TH + TH - 1) + 0.5f;

    // dead lanes start saturated so they never block the early-exit ballot
    float sum = live ? 0.0f : -1e30f;
    bool done = false;

    for (int r = 0; r < (FCHUNK + 63) / 64 && !done; ++r) {
        int fl = r * 64 + lane;
        bool ov = false;
        if (fl < FCHUNK) {
            ov = !(sbx0[fl] > wx1 || sbx1[fl] < wx0 ||
                   sby0[fl] > wy1 || sby1[fl] < wy0);
            if (ov && sFlag[fl] == 1.0f) {
                // SAT: rect separated from triangle by edge k's line with
                // >0.3px margin -> exactly zero contribution for whole tile.
                // Cross is affine in p: max over rect corners =
                // base + max(0,-7*Ey) + max(0,7*Ex).
                bool cull = false;
#pragma unroll
                for (int k = 0; k < 3; ++k) {
                    float Ex = sEx[k][fl], Ey = sEy[k][fl];
                    float base = Ex * (wy0 - sPy[k][fl]) - Ey * (wx0 - sPx[k][fl]);
                    float mx = base + fmaxf(0.0f, -7.0f * Ey)
                                    + fmaxf(0.0f,  7.0f * Ex);
                    cull |= (mx < 0.0f) & (mx * mx * sRd[k][fl] > 0.09f);
                }
                ov = !cull;
            }
        }
        unsigned long long m = __ballot(ov);

        while (m) {
            // pop two bits; duplicate+mask the second when absent so both
            // evals sit in one basic block (independent chains -> ILP)
            int f0 = __ffsll((long long)m) - 1;
            m &= m - 1;
            bool has1 = (m != 0);
            int f1 = has1 ? (__ffsll((long long)m) - 1) : f0;
            if (has1) m &= m - 1;

            float s0 = eval_face(sf, r * 64 + f0, px, py);
            float s1 = eval_face(sf, r * 64 + f1, px, py);
            sum -= s0 + (has1 ? s1 : 0.0f);

            // alpha saturation: every lane <= -30 -> 1-exp(S) is bitwise 1.0f
            // for both ref and kernel; remaining faces can't change anything.
            if (__ballot(sum <= -30.0f) == 0xFFFFFFFFFFFFFFFFull) {
                done = true;
                break;
            }
        }
    }
    // exclusive ownership of (chunk, pixel) -> plain coalesced store
    if (live) ws[(size_t)blockIdx.y * NPIX + q] = sum;
}

__global__ __launch_bounds__(BLK) void fin_kernel(
    const float* __restrict__ ws, const float* __restrict__ gt,
    float* __restrict__ out)
{
    __shared__ float wsum[BLK / 64];
    int q = blockIdx.x * BLK + threadIdx.x;
    float c = 0.0f;
    if (q < NPIX) {
        float s = 0.0f;
        for (int ch = 0; ch < NCHUNK; ++ch) s += ws[(size_t)ch * NPIX + q];
        float alpha = 1.0f - __expf(s);    // exp(very negative) -> 0 -> alpha=1
        out[1 + q] = alpha;
        c = fabsf(alpha - gt[q]);
    }
    for (int off = 32; off > 0; off >>= 1) c += __shfl_down(c, off, 64);
    if ((threadIdx.x & 63) == 0) wsum[threadIdx.x >> 6] = c;
    __syncthreads();
    if (threadIdx.x == 0) {
        float s = 0.0f;
        for (int w = 0; w < BLK / 64; ++w) s += wsum[w];
        atomicAdd(&out[0], s * (1.0f / (float)NPIX));   // out[0] zeroed by sil
    }
}

extern "C" void kernel_launch(void* const* d_in, const int* in_sizes, int n_in,
                              void* d_out, int out_size, void* d_ws, size_t ws_size,
                              hipStream_t stream)
{
    const float* verts = (const float*)d_in[0];
    const float* gt    = (const float*)d_in[1];
    const int*   faces = (const int*)d_in[2];
    float* out = (float*)d_out;          // out[0]=loss, out[1..]=sil (H*W)
    float* ws  = (float*)d_ws;           // NCHUNK * NPIX floats = 1.3 MB partials

    dim3 sgrid(NBX, NCHUNK);             // 128 x 10 = 1280 blocks
    sil_kernel<<<sgrid, BLK, 0, stream>>>(verts, faces, ws, out);

    fin_kernel<<<(NPIX + BLK - 1) / BLK, BLK, 0, stream>>>(ws, gt, out);
}